// Round 6
// baseline (59.714 us; speedup 1.0000x reference)
//
#include <hip/hip_runtime.h>
#include <hip/hip_bf16.h>

#define NB 128
#define NS 1024
#define NE 256
#define NR 64
#define NO 1024
#define NK (NE*NR)   // 16384

typedef __attribute__((ext_vector_type(8))) short short8;          // MFMA A/B frag (8 bf16)
typedef __attribute__((ext_vector_type(4))) float float4v;         // MFMA C/D frag
typedef __attribute__((ext_vector_type(4))) unsigned short ushort4v;
typedef __attribute__((ext_vector_type(8))) unsigned short ushort8v;

static __device__ inline unsigned short f2bf(float x) {
    union { float f; unsigned u; } v; v.f = x;
    unsigned r = v.u + 0x7fffu + ((v.u >> 16) & 1u);   // RNE
    return (unsigned short)(r >> 16);
}
static __device__ inline float bf2f(unsigned short h) {
    union { unsigned u; float f; } v; v.u = ((unsigned)h) << 16;
    return v.f;
}
// hardware RNE pair-convert; compiler fuses to v_cvt_pk_bf16_f32
static __device__ inline unsigned pk(float lo, float hi) {
    union { __hip_bfloat162 h2; unsigned u; } v;
    v.h2.x = __float2bfloat16(lo);
    v.h2.y = __float2bfloat16(hi);
    return v.u;
}

// ---------------------------------------------------------------------------
// k1: parts[ch][b][e][r] = sum_{s-pairs p == ch (mod 8), s<len} F[b,s,e]*R[b,s,r]
// LDS-free per-wave 32e x 64r MFMA tile; fragments loaded straight from global
// (lanes 0-15 = consecutive e / r floats -> coalesced 64B segments).
// Step = K=32 (16 s-pairs), processed as TWO half-clusters of 24 loads with
// immediate bf16 pack -> peak ~24 live floats (no spill at default VGPR cap).
// grid = NB*8 = 1024 blocks, 512 thr (8 waves = 8 e-tiles). nsteps <= 4.
// s(lane,t,word v,elem lo/hi) = 256t + 64*lgrp + 2*ch + 16*v + (0|1).
// ---------------------------------------------------------------------------
#define NCH 8

__global__ __launch_bounds__(512) void k1_mfma(
    const float* __restrict__ fillers, const float* __restrict__ roles,
    const int* __restrict__ lengths, unsigned short* __restrict__ parts)
{
    const int bid = blockIdx.x;
    const int b   = bid >> 3;
    const int ch  = bid & 7;
    const int len = lengths[b];
    const int tid = threadIdx.x;

    const int lane = tid & 63;
    const int wid  = tid >> 6;      // 0..7 : e-tile of 32
    const int lrow = lane & 15;
    const int lgrp = lane >> 4;     // 0..3

    const int e0 = wid * 32;

    // pairs p = ch + 8*idx, p < P = ceil(len/2); 16 idx per step
    const int P      = (len + 1) >> 1;
    const int count  = (P > ch) ? ((P - ch + 7) >> 3) : 0;
    const int nsteps = (count + 15) >> 4;    // <= 4

    float4v acc[2][4];   // [mf (16e)][nf (16r)]
    #pragma unroll
    for (int i = 0; i < 2; ++i)
        #pragma unroll
        for (int j = 0; j < 4; ++j)
            acc[i][j] = (float4v){0.f, 0.f, 0.f, 0.f};

    const float* fb = fillers + (size_t)b * NS * NE;
    const float* rb = roles   + (size_t)b * NS * NR;

    for (int t = 0; t < nsteps; ++t) {
        const int sb0 = 256 * t + 64 * lgrp + 2 * ch;   // per-lane-group base

        union { unsigned u[4]; short8 s8; } af[2], bf[4];

        #pragma unroll
        for (int h = 0; h < 2; ++h) {
            float a0[4], a1[4], b0[4], b1[4], b2[4], b3[4];
            #pragma unroll
            for (int j = 0; j < 4; ++j) {
                const int v = 2 * h + (j >> 1);          // frag word 0..3
                const int s = sb0 + 16 * v + (j & 1);
                const float* fr = fb + (size_t)s * NE;
                const float* rr = rb + (size_t)s * NR;
                a0[j] = fr[e0 + lrow];
                a1[j] = fr[e0 + 16 + lrow];
                b0[j] = rr[lrow];
                b1[j] = rr[16 + lrow];
                b2[j] = rr[32 + lrow];
                b3[j] = rr[48 + lrow];
            }
            // max s this half over all lanes: lgrp=3, v=2h+1, +1
            const int shi = 256 * t + 2 * ch + 192 + 16 * (2 * h + 1) + 1;
            if (shi >= len) {   // boundary half only (wave-uniform branch)
                #pragma unroll
                for (int j = 0; j < 4; ++j) {
                    const int s = sb0 + 16 * (2 * h + (j >> 1)) + (j & 1);
                    const bool ok = (s < len);
                    a0[j] = ok ? a0[j] : 0.f;  a1[j] = ok ? a1[j] : 0.f;
                    b0[j] = ok ? b0[j] : 0.f;  b1[j] = ok ? b1[j] : 0.f;
                    b2[j] = ok ? b2[j] : 0.f;  b3[j] = ok ? b3[j] : 0.f;
                }
            }
            #pragma unroll
            for (int v = 0; v < 2; ++v) {
                const int w = 2 * h + v;
                af[0].u[w] = pk(a0[2*v], a0[2*v+1]);
                af[1].u[w] = pk(a1[2*v], a1[2*v+1]);
                bf[0].u[w] = pk(b0[2*v], b0[2*v+1]);
                bf[1].u[w] = pk(b1[2*v], b1[2*v+1]);
                bf[2].u[w] = pk(b2[2*v], b2[2*v+1]);
                bf[3].u[w] = pk(b3[2*v], b3[2*v+1]);
            }
        }

        #pragma unroll
        for (int mf = 0; mf < 2; ++mf)
            #pragma unroll
            for (int nf = 0; nf < 4; ++nf)
                acc[mf][nf] = __builtin_amdgcn_mfma_f32_16x16x32_bf16(
                    af[mf].s8, bf[nf].s8, acc[mf][nf], 0, 0, 0);
    }

    // epilogue: C/D layout col=lane&15 (r), row=(lane>>4)*4+reg (e)
    // (runs even when nsteps==0: zero partial must be written — ws is poisoned)
    unsigned short* pp = parts + (size_t)(ch * NB + b) * NK;
    #pragma unroll
    for (int mf = 0; mf < 2; ++mf) {
        #pragma unroll
        for (int nf = 0; nf < 4; ++nf) {
            const int r = nf * 16 + lrow;
            #pragma unroll
            for (int reg = 0; reg < 4; ++reg) {
                const int e = e0 + mf * 16 + lgrp * 4 + reg;
                pp[(size_t)e * NR + r] = f2bf(acc[mf][nf][reg]);
            }
        }
    }
}

// ---------------------------------------------------------------------------
// k1b: tensor[i] = bf16( sum_ch parts[ch][i] )
// ---------------------------------------------------------------------------
__global__ __launch_bounds__(256) void k1b_reduce(
    const unsigned short* __restrict__ parts, unsigned short* __restrict__ tensor)
{
    const size_t i = ((size_t)blockIdx.x * 256 + threadIdx.x) * 8;
    float s[8] = {0.f,0.f,0.f,0.f,0.f,0.f,0.f,0.f};
    #pragma unroll
    for (int ch = 0; ch < NCH; ++ch) {
        ushort8v v = *(const ushort8v*)(parts + (size_t)ch * NB * NK + i);
        #pragma unroll
        for (int j = 0; j < 8; ++j)
            s[j] += bf2f(v[j]);
    }
    ushort8v o;
    #pragma unroll
    for (int j = 0; j < 8; ++j)
        o[j] = f2bf(s[j]);
    *(ushort8v*)(tensor + i) = o;
}

// ---------------------------------------------------------------------------
// k2: part[kz][b][o] = sum_{k in chunk kz} T[b][k] * W[o][k]
// BM = 128 (= NB, W read once), BN = 64, BK = 128, KSPLIT = 32.
// ---------------------------------------------------------------------------
#define BN2 64
#define BK2 128
#define KSPLIT 32
#define KC2 (NK/KSPLIT)   // 512

__global__ __launch_bounds__(512) void k2_mfma(
    const unsigned short* __restrict__ A,   // tensor bf16 [NB][NK]
    const float* __restrict__ W,            // [NO][NK]
    float* __restrict__ part)               // [KSPLIT][NB][NO]
{
    __shared__ unsigned short As[128 * BK2];  // 32 KB, XOR-swizzled 256B rows
    __shared__ unsigned short Bs[BN2 * BK2];  // 16 KB

    const int o0   = blockIdx.x * BN2;
    const int kz   = blockIdx.y;
    const int tid  = threadIdx.x;
    const int lane = tid & 63;
    const int wid  = tid >> 6;
    const int wm   = wid >> 1;   // 0..3
    const int wn   = wid & 1;    // 0..1
    const int lrow = lane & 15;
    const int lgrp = lane >> 4;

    float4v acc[2][2];
    #pragma unroll
    for (int i = 0; i < 2; ++i)
        #pragma unroll
        for (int j = 0; j < 2; ++j)
            acc[i][j] = (float4v){0.f, 0.f, 0.f, 0.f};

    for (int step = 0; step < KC2 / BK2; ++step) {   // 4
        const int kb = kz * KC2 + step * BK2;

        ushort8v av[4];
        #pragma unroll
        for (int i = 0; i < 4; ++i) {
            const int c = tid + 512 * i;           // 0..2047
            const int r = c >> 4, c16 = c & 15;    // r 0..127
            av[i] = *(const ushort8v*)(A + (size_t)r * NK + kb + c16 * 8);
        }
        float4 wv[4];
        #pragma unroll
        for (int i = 0; i < 4; ++i) {
            const int c = tid + 512 * i;
            const int r = c >> 5, c4 = c & 31;     // r 0..63
            wv[i] = *(const float4*)(W + (size_t)(o0 + r) * NK + kb + c4 * 4);
        }

        __syncthreads();

        #pragma unroll
        for (int i = 0; i < 4; ++i) {
            const int c = tid + 512 * i;
            const int r = c >> 4, c16 = c & 15;
            const int byte = (r * 256 + c16 * 16) ^ ((r & 7) << 4);
            *(ushort8v*)((char*)As + byte) = av[i];
        }
        #pragma unroll
        for (int i = 0; i < 4; ++i) {
            const int c = tid + 512 * i;
            const int r = c >> 5, c4 = c & 31;
            ushort4v bv = { f2bf(wv[i].x), f2bf(wv[i].y), f2bf(wv[i].z), f2bf(wv[i].w) };
            const int byte = (r * 256 + c4 * 8) ^ ((r & 7) << 4);
            *(ushort4v*)((char*)Bs + byte) = bv;
        }

        __syncthreads();

        #pragma unroll
        for (int kk = 0; kk < BK2; kk += 32) {
            short8 af[2], bf[2];
            #pragma unroll
            for (int mf = 0; mf < 2; ++mf) {
                const int r = wm * 32 + mf * 16 + lrow;
                const int byte = (r * 256 + (kk + lgrp * 8) * 2) ^ ((r & 7) << 4);
                af[mf] = *(const short8*)((const char*)As + byte);
            }
            #pragma unroll
            for (int nf = 0; nf < 2; ++nf) {
                const int r = wn * 32 + nf * 16 + lrow;
                const int byte = (r * 256 + (kk + lgrp * 8) * 2) ^ ((r & 7) << 4);
                bf[nf] = *(const short8*)((const char*)Bs + byte);
            }
            #pragma unroll
            for (int mf = 0; mf < 2; ++mf)
                #pragma unroll
                for (int nf = 0; nf < 2; ++nf)
                    acc[mf][nf] = __builtin_amdgcn_mfma_f32_16x16x32_bf16(
                        af[mf], bf[nf], acc[mf][nf], 0, 0, 0);
        }
    }

    float* pbase = part + (size_t)kz * NB * NO;
    #pragma unroll
    for (int mf = 0; mf < 2; ++mf) {
        #pragma unroll
        for (int nf = 0; nf < 2; ++nf) {
            const int o = o0 + wn * 32 + nf * 16 + lrow;
            #pragma unroll
            for (int reg = 0; reg < 4; ++reg) {
                const int m = wm * 32 + mf * 16 + lgrp * 4 + reg;
                pbase[(size_t)m * NO + o] = acc[mf][nf][reg];
            }
        }
    }
}

// ---------------------------------------------------------------------------
// k3: out[b][o] = bias[o] + sum_z part[z][b][o]
// ---------------------------------------------------------------------------
__global__ __launch_bounds__(256) void k3_reduce(
    const float* __restrict__ part, const float* __restrict__ bias,
    float* __restrict__ out)
{
    const int i = (blockIdx.x * 256 + threadIdx.x) * 4;
    float4 v = *(const float4*)(bias + (i & (NO - 1)));
    #pragma unroll
    for (int z = 0; z < KSPLIT; ++z) {
        float4 p = *(const float4*)(part + (size_t)z * NB * NO + i);
        v.x += p.x; v.y += p.y; v.z += p.z; v.w += p.w;
    }
    *(float4*)(out + i) = v;
}

extern "C" void kernel_launch(void* const* d_in, const int* in_sizes, int n_in,
                              void* d_out, int out_size, void* d_ws, size_t ws_size,
                              hipStream_t stream)
{
    const float* fillers = (const float*)d_in[0];
    const float* roles   = (const float*)d_in[1];
    const int*   lengths = (const int*)d_in[2];
    const float* W       = (const float*)d_in[3];
    const float* bias    = (const float*)d_in[4];
    float* out = (float*)d_out;

    // ws: [tensor bf16 4.19MB][parts bf16 8x4.19=33.6MB == overlaid part f32 16.8MB]
    unsigned short* tensor = (unsigned short*)d_ws;
    unsigned short* parts  = tensor + (size_t)NB * NK;   // k1 out, k1b in
    float*          part   = (float*)parts;              // k2 out, k3 in (disjoint lifetime)

    k1_mfma<<<NB * NCH, 512, 0, stream>>>(fillers, roles, lengths, parts);
    k1b_reduce<<<(NB * NK / 8) / 256, 256, 0, stream>>>(parts, tensor);
    dim3 g2(NO / BN2, KSPLIT);   // (16, 32)
    k2_mfma<<<g2, 512, 0, stream>>>(tensor, W, part);
    k3_reduce<<<(NB * NO) / 1024, 256, 0, stream>>>(part, bias, out);
}